// Round 2
// baseline (245.009 us; speedup 1.0000x reference)
//
#include <hip/hip_runtime.h>

#define NA 4096
#define HS 128
#define PSTR 72   // P-buffer row stride in bf16 elements (64 + 8 pad)

typedef unsigned short u16;
using bf16x8  = __attribute__((ext_vector_type(8))) short;
using f32x4   = __attribute__((ext_vector_type(4))) float;
using ushort8 = __attribute__((ext_vector_type(8))) unsigned short;

// 1/sqrt(dk)=0.25  *  log2(e)  *  0.5 (K-dim duplication in the 16x16x32 MFMA)
#define QSCALE 0.18033688011112042f

// round-to-nearest-even fp32 -> bf16 (for weights/projections)
static __device__ __forceinline__ u16 f2bf(float f) {
    unsigned u = __builtin_bit_cast(unsigned, f);
    u += 0x7FFFu + ((u >> 16) & 1u);
    return (u16)(u >> 16);
}

// ---------------------------------------------------------------------------
// Kernel 1: Q/K/V projections, fp32 VALU, bf16 outputs.
//   Qb [4096][128] bf16, pre-scaled by QSCALE
//   Kb [4096][128] bf16
//   Vt [128][4096] bf16 (transposed for contiguous PV B-fragments)
// ---------------------------------------------------------------------------
__global__ __launch_bounds__(256) void proj_all(
    const float* __restrict__ Xq, const float* __restrict__ Xk, const float* __restrict__ Xv,
    const float* __restrict__ Wq, const float* __restrict__ Wk, const float* __restrict__ Wv,
    const float* __restrict__ bq, const float* __restrict__ bk, const float* __restrict__ bv,
    u16* __restrict__ Qb, u16* __restrict__ Kb, u16* __restrict__ Vt)
{
    const int mat = blockIdx.y;  // 0=Q, 1=K, 2=V
    const float* X = (mat == 0) ? Xq : (mat == 1) ? Xk : Xv;
    const float* W = (mat == 0) ? Wq : (mat == 1) ? Wk : Wv;
    const float* B = (mat == 0) ? bq : (mat == 1) ? bk : bv;
    const int i0 = blockIdx.x * 32;

    __shared__ __align__(16) float Xs[32 * 128];
    __shared__ __align__(16) u16  Vs[32 * 128];

    const int t = threadIdx.x;
    const float4* Xg = (const float4*)(X + (size_t)i0 * HS);
    float4* Xs4 = (float4*)Xs;
#pragma unroll
    for (int idx = 0; idx < 4; ++idx) Xs4[t + idx * 256] = Xg[t + idx * 256];
    __syncthreads();

    const int jg = t & 31;   // group of 4 output cols
    const int ig = t >> 5;   // 0..7; rows i = ig + 8*rr
    const int j4 = jg * 4;

    float acc[4][4];
#pragma unroll
    for (int a = 0; a < 4; ++a)
#pragma unroll
        for (int b = 0; b < 4; ++b) acc[a][b] = 0.f;

    const float4* W4 = (const float4*)W;
#pragma unroll 4
    for (int k4 = 0; k4 < 32; ++k4) {
        float4 w0 = W4[(j4 + 0) * 32 + k4];
        float4 w1 = W4[(j4 + 1) * 32 + k4];
        float4 w2 = W4[(j4 + 2) * 32 + k4];
        float4 w3 = W4[(j4 + 3) * 32 + k4];
#pragma unroll
        for (int rr = 0; rr < 4; ++rr) {
            float4 xv = Xs4[(ig + 8 * rr) * 32 + k4];
            acc[rr][0] += xv.x * w0.x + xv.y * w0.y + xv.z * w0.z + xv.w * w0.w;
            acc[rr][1] += xv.x * w1.x + xv.y * w1.y + xv.z * w1.z + xv.w * w1.w;
            acc[rr][2] += xv.x * w2.x + xv.y * w2.y + xv.z * w2.z + xv.w * w2.w;
            acc[rr][3] += xv.x * w3.x + xv.y * w3.y + xv.z * w3.z + xv.w * w3.w;
        }
    }

    const float b0 = B[j4 + 0], b1 = B[j4 + 1], b2 = B[j4 + 2], b3 = B[j4 + 3];

    if (mat < 2) {
        u16* dst = (mat == 0) ? Qb : Kb;
        const float s = (mat == 0) ? QSCALE : 1.0f;
#pragma unroll
        for (int rr = 0; rr < 4; ++rr) {
            const int i = ig + 8 * rr;
            ushort4 sv;
            sv.x = f2bf((acc[rr][0] + b0) * s);
            sv.y = f2bf((acc[rr][1] + b1) * s);
            sv.z = f2bf((acc[rr][2] + b2) * s);
            sv.w = f2bf((acc[rr][3] + b3) * s);
            *(ushort4*)(dst + (size_t)(i0 + i) * HS + j4) = sv;
        }
    } else {
        // V: stage bf16 tile in LDS, then store transposed
#pragma unroll
        for (int rr = 0; rr < 4; ++rr) {
            const int i = ig + 8 * rr;
            ushort4 sv;
            sv.x = f2bf(acc[rr][0] + b0);
            sv.y = f2bf(acc[rr][1] + b1);
            sv.z = f2bf(acc[rr][2] + b2);
            sv.w = f2bf(acc[rr][3] + b3);
            *(ushort4*)(&Vs[i * HS + j4]) = sv;
        }
        __syncthreads();
        const int j = t & 127, seg = t >> 7;  // seg 0/1 -> i-range of 16
        ushort8 v0, v1;
#pragma unroll
        for (int ii = 0; ii < 8; ++ii) v0[ii] = Vs[(seg * 16 + ii) * HS + j];
#pragma unroll
        for (int ii = 0; ii < 8; ++ii) v1[ii] = Vs[(seg * 16 + 8 + ii) * HS + j];
        *(ushort8*)(Vt + (size_t)j * NA + i0 + seg * 16)     = v0;
        *(ushort8*)(Vt + (size_t)j * NA + i0 + seg * 16 + 8) = v1;
    }
}

// ---------------------------------------------------------------------------
// Kernel 2: fused attention + output projection.
// Block = 16 query rows, 512 threads (8 waves). Wave w owns keys
// {it*512 + w*64 .. +63 : it=0..7} and iterates all 8 heads (mask loaded
// once per (q,k), reused x8). Softmax WITHOUT max subtraction: p = 2^S
// (safe: |S| << 127 in log2 units), so partial sums/accumulators from
// different waves simply add at the end.
// ---------------------------------------------------------------------------
__global__ __launch_bounds__(512) void attn(
    const int* __restrict__ mask,
    const u16* __restrict__ Qb, const u16* __restrict__ Kb, const u16* __restrict__ Vt,
    const float* __restrict__ Wo, float* __restrict__ out)
{
    __shared__ __align__(16) u16   Pbuf[8 * 16 * PSTR];  // per-wave P tiles
    __shared__ __align__(16) float Obuf[8 * 256];        // per-wave partial O (one head)
    __shared__             float   lbuf[8 * 16];         // per-wave partial l (one head)
    __shared__ __align__(16) float xs[16 * 128];         // merged heads

    const int t = threadIdx.x;
    const int w = t >> 6;        // wave 0..7
    const int lane = t & 63;
    const int c = lane & 15;     // MFMA col / m-index
    const int q = lane >> 4;     // quad 0..3
    const int i0 = blockIdx.x * 16;

    // Q A-fragments for all heads (K-halves duplicated; x2 folded into QSCALE)
    bf16x8 qf[8];
#pragma unroll
    for (int h = 0; h < 8; ++h)
        qf[h] = *(const bf16x8*)(Qb + (size_t)(i0 + c) * HS + h * 16 + (q & 1) * 8);

    f32x4 Oacc[8];
    float lacc[8][4];
    const f32x4 zero = {0.f, 0.f, 0.f, 0.f};
#pragma unroll
    for (int h = 0; h < 8; ++h) {
        Oacc[h] = zero;
#pragma unroll
        for (int r = 0; r < 4; ++r) lacc[h][r] = 0.f;
    }

    u16* Pw = Pbuf + w * 16 * PSTR;

#pragma unroll 1
    for (int it = 0; it < 8; ++it) {
        const int kt = it * 512 + w * 64;

        // mask tile for this wave's 16x64 (q,k) block; reused across 8 heads.
        // C-layout element (row = 4q+r, col = c + 16*t4)
        float mf[4][4];
#pragma unroll
        for (int t4 = 0; t4 < 4; ++t4)
#pragma unroll
            for (int r = 0; r < 4; ++r)
                mf[t4][r] = (float)mask[(i0 + 4 * q + r) * NA + kt + t4 * 16 + c];

#pragma unroll
        for (int h = 0; h < 8; ++h) {
            // S = Q K^T (scaled to log2 domain by QSCALE in Qb)
            f32x4 S[4];
#pragma unroll
            for (int t4 = 0; t4 < 4; ++t4) {
                bf16x8 kf = *(const bf16x8*)(Kb + (size_t)(kt + t4 * 16 + c) * HS + h * 16 + (q & 1) * 8);
                S[t4] = __builtin_amdgcn_mfma_f32_16x16x32_bf16(qf[h], kf, zero, 0, 0, 0);
            }
            // p = 2^S * mask; partial row-sums in-lane; pack bf16 into LDS
#pragma unroll
            for (int t4 = 0; t4 < 4; ++t4) {
#pragma unroll
                for (int r = 0; r < 4; ++r) {
                    float p = __builtin_amdgcn_exp2f(S[t4][r]) * mf[t4][r];
                    lacc[h][r] += p;
                    unsigned u = __builtin_bit_cast(unsigned, p);
                    Pw[(4 * q + r) * PSTR + t4 * 16 + c] = (u16)((u + 0x8000u) >> 16);
                }
            }
            // Per-wave LDS drain: compiler barrier + lgkmcnt(0) + compiler barrier
            __asm__ volatile("" ::: "memory");
            __builtin_amdgcn_s_waitcnt(0xC07F);  // lgkmcnt(0), ignore vmcnt/expcnt
            __asm__ volatile("" ::: "memory");
            // O += P @ V  (A from LDS, B from transposed Vt: both contiguous 16B)
#pragma unroll
            for (int kk = 0; kk < 2; ++kk) {
                bf16x8 pf = *(const bf16x8*)(Pw + c * PSTR + kk * 32 + q * 8);
                bf16x8 vf = *(const bf16x8*)(Vt + (size_t)(h * 16 + c) * NA + kt + kk * 32 + q * 8);
                Oacc[h] = __builtin_amdgcn_mfma_f32_16x16x32_bf16(pf, vf, Oacc[h], 0, 0, 0);
            }
        }
    }

    // Combine partial O and l across the 8 waves, head by head.
#pragma unroll
    for (int h = 0; h < 8; ++h) {
        float l0 = lacc[h][0], l1 = lacc[h][1], l2 = lacc[h][2], l3 = lacc[h][3];
#pragma unroll
        for (int mm = 1; mm <= 8; mm <<= 1) {
            l0 += __shfl_xor(l0, mm, 64);
            l1 += __shfl_xor(l1, mm, 64);
            l2 += __shfl_xor(l2, mm, 64);
            l3 += __shfl_xor(l3, mm, 64);
        }
#pragma unroll
        for (int r = 0; r < 4; ++r)
            Obuf[w * 256 + (4 * q + r) * 16 + c] = Oacc[h][r];
        if (c == 0) {
            lbuf[w * 16 + 4 * q + 0] = l0;
            lbuf[w * 16 + 4 * q + 1] = l1;
            lbuf[w * 16 + 4 * q + 2] = l2;
            lbuf[w * 16 + 4 * q + 3] = l3;
        }
        __syncthreads();
        if (t < 256) {
            const int i = t >> 4, d = t & 15;
            float os = 0.f, ls = 0.f;
#pragma unroll
            for (int ww = 0; ww < 8; ++ww) {
                os += Obuf[ww * 256 + i * 16 + d];
                ls += lbuf[ww * 16 + i];
            }
            xs[i * 128 + h * 16 + d] = os / ls;
        }
        __syncthreads();
    }

    // Output projection: out[i0+i][j] = sum_k xs[i][k] * Wo[j][k]
    const int j = t & 127, ib = t >> 7;
    float acc2[4] = {0.f, 0.f, 0.f, 0.f};
    const float4* Wo4 = (const float4*)(Wo + (size_t)j * HS);
    const float4* xs4 = (const float4*)xs;
#pragma unroll 4
    for (int k4 = 0; k4 < 32; ++k4) {
        float4 wv = Wo4[k4];
#pragma unroll
        for (int rr = 0; rr < 4; ++rr) {
            float4 xv = xs4[(ib * 4 + rr) * 32 + k4];
            acc2[rr] += xv.x * wv.x + xv.y * wv.y + xv.z * wv.z + xv.w * wv.w;
        }
    }
#pragma unroll
    for (int rr = 0; rr < 4; ++rr)
        out[(size_t)(i0 + ib * 4 + rr) * HS + j] = acc2[rr];
}

extern "C" void kernel_launch(void* const* d_in, const int* in_sizes, int n_in,
                              void* d_out, int out_size, void* d_ws, size_t ws_size,
                              hipStream_t stream) {
    const float* query = (const float*)d_in[0];
    const float* key   = (const float*)d_in[1];
    const float* value = (const float*)d_in[2];
    const int*   mask  = (const int*)d_in[3];
    const float* Wq    = (const float*)d_in[4];
    const float* bq    = (const float*)d_in[5];
    const float* Wk    = (const float*)d_in[6];
    const float* bk    = (const float*)d_in[7];
    const float* Wv    = (const float*)d_in[8];
    const float* bv    = (const float*)d_in[9];
    const float* Wo    = (const float*)d_in[10];

    u16* Qb = (u16*)d_ws;
    u16* Kb = Qb + (size_t)NA * HS;
    u16* Vt = Kb + (size_t)NA * HS;

    proj_all<<<dim3(128, 3), 256, 0, stream>>>(query, key, value, Wq, Wk, Wv,
                                               bq, bk, bv, Qb, Kb, Vt);
    attn<<<dim3(256), 512, 0, stream>>>(mask, Qb, Kb, Vt, Wo, (float*)d_out);
}

// Round 3
// 226.191 us; speedup vs baseline: 1.0832x; 1.0832x over previous
//
#include <hip/hip_runtime.h>

#define NA 4096
#define HS 128
#define PSTR 72    // attn P-buffer row stride (bf16 elems)
#define CSTR 136   // proj/reduce LDS row stride (bf16 elems, 16B-aligned rows)

typedef unsigned short u16;
using bf16x8  = __attribute__((ext_vector_type(8))) short;
using f32x4   = __attribute__((ext_vector_type(4))) float;
using ushort8 = __attribute__((ext_vector_type(8))) unsigned short;

// 1/sqrt(dk)=0.25 * log2(e) * 0.5 (K-dim duplication in the 16x16x32 MFMA)
#define QSCALE 0.18033688011112042f

static __device__ __forceinline__ u16 f2bf(float f) {
    unsigned u = __builtin_bit_cast(unsigned, f);
    u += 0x7FFFu + ((u >> 16) & 1u);
    return (u16)(u >> 16);
}

// ---------------------------------------------------------------------------
// Kernel 0: convert weights to bf16. Wbuf[mat][j][k], mat: 0=Q(x QSCALE),
// 1=K, 2=V, 3=O. bb[mat][j] f32 biases (bq pre-scaled).
// ---------------------------------------------------------------------------
__global__ __launch_bounds__(256) void cvt_w(
    const float* __restrict__ Wq, const float* __restrict__ Wk,
    const float* __restrict__ Wv, const float* __restrict__ Wo,
    const float* __restrict__ bq, const float* __restrict__ bk,
    const float* __restrict__ bv,
    u16* __restrict__ Wbuf, float* __restrict__ bb)
{
    const int gid = blockIdx.x * 256 + threadIdx.x;   // 16384 threads
    const int e = gid * 4;                            // 4 elems each
    const int mat = e >> 14, off = e & 16383;
    const float* src = (mat == 0) ? Wq : (mat == 1) ? Wk : (mat == 2) ? Wv : Wo;
    const float s = (mat == 0) ? QSCALE : 1.0f;
    float4 v = *(const float4*)(src + off);
    ushort4 o;
    o.x = f2bf(v.x * s); o.y = f2bf(v.y * s);
    o.z = f2bf(v.z * s); o.w = f2bf(v.w * s);
    *(ushort4*)(Wbuf + e) = o;
    if (gid < 128)      bb[gid] = bq[gid] * QSCALE;
    else if (gid < 256) bb[gid] = bk[gid - 128];
    else if (gid < 384) bb[gid] = bv[gid - 256];
}

// ---------------------------------------------------------------------------
// Kernel 1: Q/K/V projections via MFMA. Block = 128 thr (2 waves), each wave
// 16 rows x 128 cols of one matrix. A = X rows (f32 -> bf16 on the fly),
// B = W rows (bf16). Qb/Kb row-major; Vt transposed [dim][row].
// ---------------------------------------------------------------------------
__global__ __launch_bounds__(128) void proj_mfma(
    const float* __restrict__ Xq, const float* __restrict__ Xk, const float* __restrict__ Xv,
    const u16* __restrict__ Wbuf, const float* __restrict__ bb,
    u16* __restrict__ Qb, u16* __restrict__ Kb, u16* __restrict__ Vt)
{
    const int mat = blockIdx.y;
    const float* X = (mat == 0) ? Xq : (mat == 1) ? Xk : Xv;
    const u16* Wm = Wbuf + mat * 16384;
    const float* bm = bb + mat * 128;

    const int t = threadIdx.x;
    const int wv = t >> 6, lane = t & 63;
    const int c = lane & 15, q = lane >> 4;
    const int r0 = blockIdx.x * 32 + wv * 16;

    __shared__ __align__(16) u16 Cs[2 * 16 * CSTR];
    u16* Csw = Cs + wv * 16 * CSTR;

    // A fragments: X row (r0+c), k = kk*32 + q*8 .. +7  (f32 -> bf16)
    bf16x8 af[4];
    const float* Xr = X + (size_t)(r0 + c) * HS;
#pragma unroll
    for (int kk = 0; kk < 4; ++kk) {
        float4 xa = *(const float4*)(Xr + kk * 32 + q * 8);
        float4 xb = *(const float4*)(Xr + kk * 32 + q * 8 + 4);
        bf16x8 v;
        v[0] = (short)f2bf(xa.x); v[1] = (short)f2bf(xa.y);
        v[2] = (short)f2bf(xa.z); v[3] = (short)f2bf(xa.w);
        v[4] = (short)f2bf(xb.x); v[5] = (short)f2bf(xb.y);
        v[6] = (short)f2bf(xb.z); v[7] = (short)f2bf(xb.w);
        af[kk] = v;
    }

    const f32x4 zero = {0.f, 0.f, 0.f, 0.f};
#pragma unroll
    for (int j0 = 0; j0 < 8; ++j0) {
        f32x4 acc = zero;
#pragma unroll
        for (int kk = 0; kk < 4; ++kk) {
            bf16x8 bf = *(const bf16x8*)(Wm + (size_t)(j0 * 16 + c) * HS + kk * 32 + q * 8);
            acc = __builtin_amdgcn_mfma_f32_16x16x32_bf16(af[kk], bf, acc, 0, 0, 0);
        }
        const float bias = bm[j0 * 16 + c];
        // D element: row (query) = 4q+r, col = j0*16+c
#pragma unroll
        for (int r = 0; r < 4; ++r)
            Csw[(4 * q + r) * CSTR + j0 * 16 + c] = f2bf(acc[r] + bias);
    }
    __asm__ volatile("" ::: "memory");
    __builtin_amdgcn_s_waitcnt(0xC07F);  // drain LDS writes (per-wave)
    __asm__ volatile("" ::: "memory");

    if (mat < 2) {
        u16* dst = (mat == 0) ? Qb : Kb;
        const int row = lane >> 2;
#pragma unroll
        for (int ss = 0; ss < 4; ++ss) {
            const int s4 = (lane & 3) + 4 * ss;
            bf16x8 vv = *(const bf16x8*)(Csw + row * CSTR + s4 * 8);
            *(bf16x8*)(dst + (size_t)(r0 + row) * HS + s4 * 8) = vv;
        }
    } else {
#pragma unroll
        for (int half = 0; half < 2; ++half) {
            const int j = lane + half * 64;
            ushort8 v0, v1;
#pragma unroll
            for (int ii = 0; ii < 8; ++ii) v0[ii] = Csw[ii * CSTR + j];
#pragma unroll
            for (int ii = 0; ii < 8; ++ii) v1[ii] = Csw[(8 + ii) * CSTR + j];
            *(ushort8*)(Vt + (size_t)j * NA + r0)     = v0;
            *(ushort8*)(Vt + (size_t)j * NA + r0 + 8) = v1;
        }
    }
}

// ---------------------------------------------------------------------------
// Kernel 2: attention partials. Grid (256 tiles, 3 key-splits), 512 thr =
// 8 waves, wave = one head. No block barriers in the main loop; each wave
// has a private P buffer. p = 2^S (no max subtraction) so partials add.
// Partials: part[tile][split][head][272] = { O 16x16 f32, l 16 f32 }.
// ---------------------------------------------------------------------------
__global__ __launch_bounds__(512, 6) void attn(
    const int* __restrict__ mask,
    const u16* __restrict__ Qb, const u16* __restrict__ Kb, const u16* __restrict__ Vt,
    float* __restrict__ part)
{
    __shared__ __align__(16) u16 Pbuf[8 * 16 * PSTR];

    const int t = threadIdx.x;
    const int h = t >> 6;        // wave = head
    const int lane = t & 63;
    const int c = lane & 15;
    const int q = lane >> 4;
    const int tile = blockIdx.x, split = blockIdx.y;
    const int i0 = tile * 16;
    const int kt0 = (split == 0) ? 0 : (split == 1) ? 1408 : 2752;
    const int nit = (split == 0) ? 22 : 21;

    // Q A-fragment (K-halves duplicated; x2 folded into QSCALE)
    const bf16x8 qf = *(const bf16x8*)(Qb + (size_t)(i0 + c) * HS + h * 16 + (q & 1) * 8);

    const f32x4 zero = {0.f, 0.f, 0.f, 0.f};
    f32x4 Oacc = zero;
    float lacc[4] = {0.f, 0.f, 0.f, 0.f};

    u16* Pw = Pbuf + h * 16 * PSTR;

#pragma unroll 1
    for (int it = 0; it < nit; ++it) {
        const int kt = kt0 + it * 64;

        // mask tile 16x64: element (row=4q+r, col=t4*16+c)
        float mf[4][4];
#pragma unroll
        for (int t4 = 0; t4 < 4; ++t4)
#pragma unroll
            for (int r = 0; r < 4; ++r)
                mf[t4][r] = (float)mask[(size_t)(i0 + 4 * q + r) * NA + kt + t4 * 16 + c];

        // S = Q K^T (log2 domain)
        f32x4 S[4];
#pragma unroll
        for (int t4 = 0; t4 < 4; ++t4) {
            bf16x8 kf = *(const bf16x8*)(Kb + (size_t)(kt + t4 * 16 + c) * HS + h * 16 + (q & 1) * 8);
            S[t4] = __builtin_amdgcn_mfma_f32_16x16x32_bf16(qf, kf, zero, 0, 0, 0);
        }
        // p = 2^S * mask; row partial sums; pack bf16 P into LDS
#pragma unroll
        for (int t4 = 0; t4 < 4; ++t4) {
#pragma unroll
            for (int r = 0; r < 4; ++r) {
                float p = __builtin_amdgcn_exp2f(S[t4][r]) * mf[t4][r];
                lacc[r] += p;
                unsigned u = __builtin_bit_cast(unsigned, p);
                Pw[(4 * q + r) * PSTR + t4 * 16 + c] = (u16)((u + 0x8000u) >> 16);
            }
        }
        __asm__ volatile("" ::: "memory");
        __builtin_amdgcn_s_waitcnt(0xC07F);  // per-wave LDS drain
        __asm__ volatile("" ::: "memory");
        // O += P @ V
#pragma unroll
        for (int kk = 0; kk < 2; ++kk) {
            bf16x8 pf = *(const bf16x8*)(Pw + c * PSTR + kk * 32 + q * 8);
            bf16x8 vf = *(const bf16x8*)(Vt + (size_t)(h * 16 + c) * NA + kt + kk * 32 + q * 8);
            Oacc = __builtin_amdgcn_mfma_f32_16x16x32_bf16(pf, vf, Oacc, 0, 0, 0);
        }
    }

    // reduce l over the 16 column-lanes
    float l0 = lacc[0], l1 = lacc[1], l2 = lacc[2], l3 = lacc[3];
#pragma unroll
    for (int mm = 1; mm <= 8; mm <<= 1) {
        l0 += __shfl_xor(l0, mm, 64);
        l1 += __shfl_xor(l1, mm, 64);
        l2 += __shfl_xor(l2, mm, 64);
        l3 += __shfl_xor(l3, mm, 64);
    }

    float* base = part + (size_t)((tile * 3 + split) * 8 + h) * 272;
#pragma unroll
    for (int r = 0; r < 4; ++r)
        base[(4 * q + r) * 16 + c] = Oacc[r];
    if (c == 0) {
        base[256 + 4 * q + 0] = l0;
        base[256 + 4 * q + 1] = l1;
        base[256 + 4 * q + 2] = l2;
        base[256 + 4 * q + 3] = l3;
    }
}

// ---------------------------------------------------------------------------
// Kernel 3: combine split partials, normalize, output projection via MFMA.
// Grid 256 (row tiles), 256 thr (4 waves; wave handles 2 col-tiles of Wo).
// ---------------------------------------------------------------------------
__global__ __launch_bounds__(256) void reduce_out(
    const float* __restrict__ part, const u16* __restrict__ Wbuf,
    float* __restrict__ out)
{
    __shared__ __align__(16) u16 xs[16 * CSTR];

    const int t = threadIdx.x;
    const int tile = blockIdx.x;
    const int i0 = tile * 16;
    const float* Pt = part + (size_t)tile * 3 * 8 * 272;

    {
        const int i = t >> 4, d = t & 15;
#pragma unroll
        for (int h = 0; h < 8; ++h) {
            float os = 0.f, ls = 0.f;
#pragma unroll
            for (int s = 0; s < 3; ++s) {
                const float* b = Pt + (size_t)(s * 8 + h) * 272;
                os += b[i * 16 + d];
                ls += b[256 + i];
            }
            xs[i * CSTR + h * 16 + d] = f2bf(os / ls);
        }
    }
    __syncthreads();

    const int wv = t >> 6, lane = t & 63;
    const int c = lane & 15, q = lane >> 4;
    const u16* WoB = Wbuf + 3 * 16384;

    bf16x8 af[4];
#pragma unroll
    for (int kk = 0; kk < 4; ++kk)
        af[kk] = *(const bf16x8*)(xs + c * CSTR + kk * 32 + q * 8);

    const f32x4 zero = {0.f, 0.f, 0.f, 0.f};
#pragma unroll
    for (int jj = 0; jj < 2; ++jj) {
        const int j0 = wv * 2 + jj;
        f32x4 acc = zero;
#pragma unroll
        for (int kk = 0; kk < 4; ++kk) {
            bf16x8 bf = *(const bf16x8*)(WoB + (size_t)(j0 * 16 + c) * HS + kk * 32 + q * 8);
            acc = __builtin_amdgcn_mfma_f32_16x16x32_bf16(af[kk], bf, acc, 0, 0, 0);
        }
#pragma unroll
        for (int r = 0; r < 4; ++r)
            out[(size_t)(i0 + 4 * q + r) * HS + j0 * 16 + c] = acc[r];
    }
}

extern "C" void kernel_launch(void* const* d_in, const int* in_sizes, int n_in,
                              void* d_out, int out_size, void* d_ws, size_t ws_size,
                              hipStream_t stream) {
    const float* query = (const float*)d_in[0];
    const float* key   = (const float*)d_in[1];
    const float* value = (const float*)d_in[2];
    const int*   mask  = (const int*)d_in[3];
    const float* Wq    = (const float*)d_in[4];
    const float* bq    = (const float*)d_in[5];
    const float* Wk    = (const float*)d_in[6];
    const float* bk    = (const float*)d_in[7];
    const float* Wv    = (const float*)d_in[8];
    const float* bv    = (const float*)d_in[9];
    const float* Wo    = (const float*)d_in[10];

    u16* Qb   = (u16*)d_ws;                    // 1 MB
    u16* Kb   = Qb + (size_t)NA * HS;          // 1 MB
    u16* Vt   = Kb + (size_t)NA * HS;          // 1 MB
    u16* Wbuf = Vt + (size_t)NA * HS;          // 128 KB
    float* bb   = (float*)(Wbuf + 4 * 16384);  // 1.5 KB
    float* partb = bb + 384;                   // 256*3*8*272 f32 = 6.7 MB

    cvt_w<<<64, 256, 0, stream>>>(Wq, Wk, Wv, Wo, bq, bk, bv, Wbuf, bb);
    proj_mfma<<<dim3(128, 3), 128, 0, stream>>>(query, key, value, Wbuf, bb, Qb, Kb, Vt);
    attn<<<dim3(256, 3), 512, 0, stream>>>(mask, Qb, Kb, Vt, partb);
    reduce_out<<<256, 256, 0, stream>>>(partb, Wbuf, (float*)d_out);
}